// Round 1
// 2041.475 us; speedup vs baseline: 1.1575x; 1.1575x over previous
//
#include <hip/hip_runtime.h>
#include <hip/hip_bf16.h>
#include <cstdint>
#include <cstddef>
#include <math.h>

#define T_TOK 2048
#define DMODEL 1280
#define NHEAD 16
#define HDIM 80
#define HALFD 40
#define FFDIM 3420
#define FF_PAD 3456        /* 27*128, N-pad for gate/up GEMM C */
#define FFK_PAD 3424       /* 107*32, K-pad for down GEMM A    */
#define PATCH_INDIM 1176
#define PATCHK_PAD 1184    /* 37*32 */
#define DEPTH_L 4
#define OUTD 3584
#define WIN 64
#define NWIN (T_TOK / WIN)
#define MERGED 5120
#define EPSV 1e-6f
#define SCALE_ATTN 0.11180339887498949f

typedef __attribute__((ext_vector_type(8))) short short8;
typedef __attribute__((ext_vector_type(4))) float f32x4;
typedef unsigned short ushort_t;

// ---------------------------------------------------------------------------
// bf16 MFMA GEMM, latency-hiding pipeline version:
//   C[M,Nc]fp32 = A[M,Kp]bf16 @ Bt[N,Kp]bf16^T  (+bias, +res)
// BM=BN=128, BK=32, 256 thr = 4 waves, each wave 64x64 via 4x4 16x16x32 MFMAs.
// 3-stage LDS triple-buffer (48 KiB), 2-tiles-ahead prefetch with counted
// s_waitcnt vmcnt(4) + raw s_barrier (loads stay in flight across barriers).
// T2 XOR-swizzle on the 16B chunk index (pre-swizzled GLOBAL source, linear
// global_load_lds dest, swizzled ds_read) kills the 8-way bank conflict.
// T1 bijective XCD block swizzle. T5 setprio around the MFMA cluster.
// Requires M%128==0, Nc%128==0, Kp%32==0. Epilogue guarded by col<Nreal.
// ---------------------------------------------------------------------------
__global__ __launch_bounds__(256) void gemm_bf16(
    const ushort_t* __restrict__ A, const ushort_t* __restrict__ Bt,
    const float* __restrict__ bias, const float* __restrict__ res,
    float* __restrict__ C, int M, int Nreal, int Nc, int Kp)
{
    __shared__ ushort_t As[3][128 * 32];
    __shared__ ushort_t Bs[3][128 * 32];

    const int tid  = threadIdx.x;
    const int lane = tid & 63;
    const int wave = tid >> 6;

    // T1: bijective XCD-aware block swizzle (m204 variant)
    const int nwg = gridDim.x * gridDim.y;
    int lin = blockIdx.y * gridDim.x + blockIdx.x;
    {
        const int q = nwg >> 3, r = nwg & 7;
        const int xcd = lin & 7, j = lin >> 3;
        lin = (xcd < r ? xcd * (q + 1) : r * (q + 1) + (xcd - r) * q) + j;
    }
    const int row0 = (lin / gridDim.x) * 128;
    const int col0 = (lin % gridDim.x) * 128;
    const int wm0  = (wave & 1) * 64;
    const int wn0  = (wave >> 1) * 64;

    f32x4 acc[4][4] = {};

    const int ldr = tid >> 2;                       // 0..63 staging row (per 64-row half)
    const int ldc = ((tid & 3) ^ (ldr & 3)) * 8;    // T2: pre-swizzled source chunk

    const int mrow = lane & 15;
    const int kswz = ((lane >> 4) ^ (mrow & 3)) * 8; // T2: swizzled read chunk
    const int nt   = Kp >> 5;

    auto stage = [&](int buf, int kk) {
        const ushort_t* ga = A  + (size_t)(row0 + ldr) * Kp + kk + ldc;
        const ushort_t* gb = Bt + (size_t)(col0 + ldr) * Kp + kk + ldc;
        __builtin_amdgcn_global_load_lds(
            (const __attribute__((address_space(1))) void*)ga,
            (__attribute__((address_space(3))) void*)(&As[buf][tid * 8]), 16, 0, 0);
        __builtin_amdgcn_global_load_lds(
            (const __attribute__((address_space(1))) void*)(ga + (size_t)64 * Kp),
            (__attribute__((address_space(3))) void*)(&As[buf][2048 + tid * 8]), 16, 0, 0);
        __builtin_amdgcn_global_load_lds(
            (const __attribute__((address_space(1))) void*)gb,
            (__attribute__((address_space(3))) void*)(&Bs[buf][tid * 8]), 16, 0, 0);
        __builtin_amdgcn_global_load_lds(
            (const __attribute__((address_space(1))) void*)(gb + (size_t)64 * Kp),
            (__attribute__((address_space(3))) void*)(&Bs[buf][2048 + tid * 8]), 16, 0, 0);
    };

    // Prologue: stage tiles 0 and 1 (4 vm ops each)
    stage(0, 0);
    if (nt > 1) stage(1, 32);

    int cur = 0;
    for (int t = 0; t < nt; ++t) {
        // Wait for tile t only (its 4 loads are the oldest); keep the rest in flight.
        if (t + 1 < nt) asm volatile("s_waitcnt vmcnt(4)" ::: "memory");
        else            asm volatile("s_waitcnt vmcnt(0)" ::: "memory");
        __builtin_amdgcn_s_barrier();

        short8 af[4], bf[4];
        #pragma unroll
        for (int i = 0; i < 4; i++) {
            af[i] = *(const short8*)&As[cur][(wm0 + i * 16 + mrow) * 32 + kswz];
            bf[i] = *(const short8*)&Bs[cur][(wn0 + i * 16 + mrow) * 32 + kswz];
        }
        __builtin_amdgcn_s_setprio(1);
        #pragma unroll
        for (int i = 0; i < 4; i++)
            #pragma unroll
            for (int j = 0; j < 4; j++)
                acc[i][j] = __builtin_amdgcn_mfma_f32_16x16x32_bf16(
                    af[i], bf[j], acc[i][j], 0, 0, 0);
        __builtin_amdgcn_s_setprio(0);

        // Prefetch tile t+2 into the buffer freed this iteration two iters ago.
        // Safe: all waves passed this iteration's barrier, so nobody is still
        // reading buf (t+2)%3 (== (t-1)%3), and it differs from cur and cur+1.
        if (t + 2 < nt) {
            int pf = cur + 2; if (pf >= 3) pf -= 3;
            stage(pf, (t + 2) * 32);
        }
        cur = (cur == 2) ? 0 : cur + 1;
    }

    const int crow0 = row0 + wm0 + (lane >> 4) * 4;
    const int ccol0 = col0 + wn0 + (lane & 15);
    #pragma unroll
    for (int j = 0; j < 4; j++) {
        const int col = ccol0 + j * 16;
        if (col >= Nreal) continue;
        const float bv = bias ? bias[col] : 0.f;
        #pragma unroll
        for (int i = 0; i < 4; i++) {
            #pragma unroll
            for (int r = 0; r < 4; r++) {
                const int row = crow0 + i * 16 + r;
                float v = acc[i][j][r] + bv;
                if (res) v += res[(size_t)row * Nc + col];
                C[(size_t)row * Nc + col] = v;
            }
        }
    }
}

// ---------------------------------------------------------------------------
// Tiled transpose + fp32->bf16: in[K,N] fp32 -> out[Np,Kp] bf16 (zero-padded)
// ---------------------------------------------------------------------------
__global__ __launch_bounds__(256) void transpose_cvt(
    const float* __restrict__ in, __hip_bfloat16* __restrict__ out,
    int K, int N, int Kp, int Np)
{
    __shared__ float t[32][33];
    const int k0 = blockIdx.x * 32, n0 = blockIdx.y * 32;
    const int tx = threadIdx.x & 31, ty = threadIdx.x >> 5;  // 32x8
    #pragma unroll
    for (int i = 0; i < 4; i++) {
        const int k = k0 + ty + i * 8, n = n0 + tx;
        t[ty + i * 8][tx] = (k < K && n < N) ? in[(size_t)k * N + n] : 0.f;
    }
    __syncthreads();
    #pragma unroll
    for (int i = 0; i < 4; i++) {
        const int n = n0 + ty + i * 8, k = k0 + tx;
        if (n < Np && k < Kp)
            out[(size_t)n * Kp + k] = __float2bfloat16(t[tx][ty + i * 8]);
    }
}

// fp32 [M,K] -> bf16 [M,Kp] with zero pad (row-major, no transpose)
__global__ __launch_bounds__(256) void cvt_pad(
    const float* __restrict__ in, __hip_bfloat16* __restrict__ out,
    int M, int K, int Kp)
{
    const int i = blockIdx.x * 256 + threadIdx.x;
    if (i >= M * Kp) return;
    const int m = i / Kp, k = i - m * Kp;
    out[i] = __float2bfloat16(k < K ? in[(size_t)m * K + k] : 0.f);
}

// ---------------------------------------------------------------------------
// RMSNorm fp32 in -> bf16 out. One block per row.
// ---------------------------------------------------------------------------
__global__ __launch_bounds__(256) void rmsnorm_kernel(
    const float* __restrict__ x, const float* __restrict__ scale,
    __hip_bfloat16* __restrict__ out, int D)
{
    const int row = blockIdx.x;
    const float* xr = x + (size_t)row * D;
    float ss = 0.f;
    for (int i = threadIdx.x; i < D; i += 256) { const float v = xr[i]; ss += v * v; }
    for (int off = 32; off > 0; off >>= 1) ss += __shfl_down(ss, off);
    __shared__ float red[4];
    if ((threadIdx.x & 63) == 0) red[threadIdx.x >> 6] = ss;
    __syncthreads();
    const float tot = red[0] + red[1] + red[2] + red[3];
    const float inv = rsqrtf(tot / (float)D + EPSV);
    __hip_bfloat16* orow = out + (size_t)row * D;
    for (int i = threadIdx.x; i < D; i += 256)
        orow[i] = __float2bfloat16(xr[i] * scale[i] * inv);
}

// ---------------------------------------------------------------------------
// RoPE in-place on fp32 qkv (T, 3*D)
// ---------------------------------------------------------------------------
__global__ __launch_bounds__(256) void rope_kernel(
    float* __restrict__ qkv, const float* __restrict__ rpe)
{
    const int i = blockIdx.x * 256 + threadIdx.x;
    if (i >= T_TOK * NHEAD * HALFD) return;
    const int t = i / (NHEAD * HALFD);
    const int rem = i - t * (NHEAD * HALFD);
    const int hh = rem / HALFD;
    const int j = rem - hh * HALFD;
    const float ang = rpe[t * HALFD + j];
    const float c = cosf(ang), s = sinf(ang);
    const size_t qb = (size_t)t * (3 * DMODEL) + hh * HDIM + j;
    float r = qkv[qb], im = qkv[qb + HALFD];
    qkv[qb] = r * c - im * s;
    qkv[qb + HALFD] = r * s + im * c;
    const size_t kb = qb + DMODEL;
    r = qkv[kb]; im = qkv[kb + HALFD];
    qkv[kb] = r * c - im * s;
    qkv[kb + HALFD] = r * s + im * c;
}

// ---------------------------------------------------------------------------
// Windowed attention (fp32 math), writes bf16 o. One block per (window, head).
// ---------------------------------------------------------------------------
__global__ __launch_bounds__(256) void attn_kernel(
    const float* __restrict__ qkv, __hip_bfloat16* __restrict__ o)
{
    __shared__ float qs[WIN][HDIM + 1];
    __shared__ float ks[WIN][HDIM + 1];   // reused for v
    __shared__ float ps[WIN][WIN];
    const int win = blockIdx.x, hh = blockIdx.y;
    const int t0 = win * WIN;
    const int tid = threadIdx.x;

    for (int i = tid; i < WIN * HDIM; i += 256) {
        const int r = i / HDIM, d = i - r * HDIM;
        const size_t base = (size_t)(t0 + r) * (3 * DMODEL) + hh * HDIM + d;
        qs[r][d] = qkv[base];
        ks[r][d] = qkv[base + DMODEL];
    }
    __syncthreads();

    const int row = tid >> 2, sub = tid & 3;
    float s[16];
    #pragma unroll
    for (int jj = 0; jj < 16; jj++) s[jj] = 0.f;
    for (int d = 0; d < HDIM; d++) {
        const float qv = qs[row][d];
        #pragma unroll
        for (int jj = 0; jj < 16; jj++) s[jj] += qv * ks[sub * 16 + jj][d];
    }
    float mx = -1e30f;
    #pragma unroll
    for (int jj = 0; jj < 16; jj++) { s[jj] *= SCALE_ATTN; mx = fmaxf(mx, s[jj]); }
    for (int off = 1; off < 4; off <<= 1) mx = fmaxf(mx, __shfl_xor(mx, off));
    float l = 0.f;
    #pragma unroll
    for (int jj = 0; jj < 16; jj++) { s[jj] = expf(s[jj] - mx); l += s[jj]; }
    for (int off = 1; off < 4; off <<= 1) l += __shfl_xor(l, off);
    const float inv = 1.f / l;
    #pragma unroll
    for (int jj = 0; jj < 16; jj++) ps[row][sub * 16 + jj] = s[jj] * inv;
    __syncthreads();

    for (int i = tid; i < WIN * HDIM; i += 256) {
        const int r = i / HDIM, d = i - r * HDIM;
        ks[r][d] = qkv[(size_t)(t0 + r) * (3 * DMODEL) + 2 * DMODEL + hh * HDIM + d];
    }
    __syncthreads();

    for (int i = tid; i < WIN * HDIM; i += 256) {
        const int r = i / HDIM, d = i - r * HDIM;
        float acc = 0.f;
        #pragma unroll
        for (int j = 0; j < WIN; j++) acc += ps[r][j] * ks[j][d];
        o[(size_t)(t0 + r) * DMODEL + hh * HDIM + d] = __float2bfloat16(acc);
    }
}

// ---------------------------------------------------------------------------
// silu(g)*u: g,u fp32 [T, FF_PAD] (cols<FFDIM valid) -> bf16 [T, FFK_PAD]
// ---------------------------------------------------------------------------
__global__ __launch_bounds__(256) void silumul_kernel(
    const float* __restrict__ g, const float* __restrict__ u,
    __hip_bfloat16* __restrict__ out)
{
    const int i = blockIdx.x * 256 + threadIdx.x;
    if (i >= T_TOK * FFK_PAD) return;
    const int row = i / FFK_PAD, k = i - row * FFK_PAD;
    float v = 0.f;
    if (k < FFDIM) {
        const float x = g[(size_t)row * FF_PAD + k];
        v = (x / (1.f + expf(-x))) * u[(size_t)row * FF_PAD + k];
    }
    out[i] = __float2bfloat16(v);
}

// gelu exact on fp32 [n] -> bf16 [n]
__global__ __launch_bounds__(256) void gelu_kernel(
    const float* __restrict__ x, __hip_bfloat16* __restrict__ out, int n)
{
    const int i = blockIdx.x * 256 + threadIdx.x;
    if (i < n) {
        const float v = x[i];
        out[i] = __float2bfloat16(0.5f * v * (1.f + erff(v * 0.70710678118654752f)));
    }
}

// ---------------------------------------------------------------------------
extern "C" void kernel_launch(void* const* d_in, const int* in_sizes, int n_in,
                              void* d_out, int out_size, void* d_ws, size_t ws_size,
                              hipStream_t stream)
{
    const float* x       = (const float*)d_in[0];
    const float* rpe     = (const float*)d_in[1];
    const float* patch_w = (const float*)d_in[3];
    const float* qkv_w   = (const float*)d_in[4];
    const float* qkv_b   = (const float*)d_in[5];
    const float* proj_w  = (const float*)d_in[6];
    const float* proj_b  = (const float*)d_in[7];
    const float* norm1_s = (const float*)d_in[8];
    const float* norm2_s = (const float*)d_in[9];
    const float* gate_w  = (const float*)d_in[10];
    const float* gate_b  = (const float*)d_in[11];
    const float* up_w    = (const float*)d_in[12];
    const float* up_b    = (const float*)d_in[13];
    const float* down_w  = (const float*)d_in[14];
    const float* down_b  = (const float*)d_in[15];
    const float* lnq_s   = (const float*)d_in[16];
    const float* fc1_w   = (const float*)d_in[17];
    const float* fc1_b   = (const float*)d_in[18];
    const float* fc2_w   = (const float*)d_in[19];
    const float* fc2_b   = (const float*)d_in[20];
    float* out = (float*)d_out;

    char* p = (char*)d_ws;
    auto alloc = [&](size_t bytes) -> void* {
        void* r = (void*)p; p += (bytes + 255) & ~(size_t)255; return r;
    };
    // fp32 buffers
    float* h    = (float*)alloc((size_t)T_TOK * DMODEL * 4);
    float* qkvf = (float*)alloc((size_t)T_TOK * 3 * DMODEL * 4);
    float* gf   = (float*)alloc((size_t)T_TOK * FF_PAD * 4);
    float* uf   = (float*)alloc((size_t)T_TOK * FF_PAD * 4);
    float* fc1f = (float*)alloc((size_t)512 * MERGED * 4);
    // bf16 buffers
    __hip_bfloat16* x_b    = (__hip_bfloat16*)alloc((size_t)T_TOK * PATCHK_PAD * 2);
    __hip_bfloat16* n_b    = (__hip_bfloat16*)alloc((size_t)T_TOK * DMODEL * 2);
    __hip_bfloat16* o_b    = (__hip_bfloat16*)alloc((size_t)T_TOK * DMODEL * 2);
    __hip_bfloat16* g_b    = (__hip_bfloat16*)alloc((size_t)T_TOK * FFK_PAD * 2);
    __hip_bfloat16* m_b    = (__hip_bfloat16*)alloc((size_t)512 * MERGED * 2);
    __hip_bfloat16* patch_t= (__hip_bfloat16*)alloc((size_t)DMODEL * PATCHK_PAD * 2);
    __hip_bfloat16* qkv_t  = (__hip_bfloat16*)alloc((size_t)3 * DMODEL * DMODEL * 2);
    __hip_bfloat16* proj_t = (__hip_bfloat16*)alloc((size_t)DMODEL * DMODEL * 2);
    __hip_bfloat16* gate_t = (__hip_bfloat16*)alloc((size_t)FF_PAD * DMODEL * 2);
    __hip_bfloat16* up_t   = (__hip_bfloat16*)alloc((size_t)FF_PAD * DMODEL * 2);
    __hip_bfloat16* down_t = (__hip_bfloat16*)alloc((size_t)DMODEL * FFK_PAD * 2);
    __hip_bfloat16* fc1_t  = (__hip_bfloat16*)alloc((size_t)MERGED * MERGED * 2);
    __hip_bfloat16* fc2_t  = (__hip_bfloat16*)alloc((size_t)OUTD * MERGED * 2);

    const dim3 blk(256);
    auto gemm = [&](const __hip_bfloat16* A, const __hip_bfloat16* Bt,
                    const float* bias, const float* res, float* C,
                    int M, int Nreal, int Nc, int Kp) {
        dim3 grid(Nc / 128, M / 128);
        gemm_bf16<<<grid, blk, 0, stream>>>((const ushort_t*)A, (const ushort_t*)Bt,
                                            bias, res, C, M, Nreal, Nc, Kp);
    };
    auto tcvt = [&](const float* in, __hip_bfloat16* o2, int K, int N, int Kp, int Np) {
        dim3 grid((Kp + 31) / 32, (Np + 31) / 32);
        transpose_cvt<<<grid, blk, 0, stream>>>(in, o2, K, N, Kp, Np);
    };

    // one-time (per call) conversions
    cvt_pad<<<(T_TOK * PATCHK_PAD + 255) / 256, blk, 0, stream>>>(
        x, x_b, T_TOK, PATCH_INDIM, PATCHK_PAD);
    tcvt(patch_w, patch_t, PATCH_INDIM, DMODEL, PATCHK_PAD, DMODEL);
    tcvt(fc1_w, fc1_t, MERGED, MERGED, MERGED, MERGED);
    tcvt(fc2_w, fc2_t, MERGED, OUTD, MERGED, OUTD);

    // h = x @ patch_w
    gemm(x_b, patch_t, nullptr, nullptr, h, T_TOK, DMODEL, DMODEL, PATCHK_PAD);

    for (int l = 0; l < DEPTH_L; l++) {
        tcvt(qkv_w + (size_t)l * DMODEL * 3 * DMODEL, qkv_t, DMODEL, 3 * DMODEL,
             DMODEL, 3 * DMODEL);
        tcvt(proj_w + (size_t)l * DMODEL * DMODEL, proj_t, DMODEL, DMODEL,
             DMODEL, DMODEL);
        tcvt(gate_w + (size_t)l * DMODEL * FFDIM, gate_t, DMODEL, FFDIM,
             DMODEL, FF_PAD);
        tcvt(up_w + (size_t)l * DMODEL * FFDIM, up_t, DMODEL, FFDIM,
             DMODEL, FF_PAD);
        tcvt(down_w + (size_t)l * FFDIM * DMODEL, down_t, FFDIM, DMODEL,
             FFK_PAD, DMODEL);

        rmsnorm_kernel<<<T_TOK, blk, 0, stream>>>(h, norm1_s + l * DMODEL, n_b, DMODEL);
        gemm(n_b, qkv_t, qkv_b + l * 3 * DMODEL, nullptr, qkvf,
             T_TOK, 3 * DMODEL, 3 * DMODEL, DMODEL);
        rope_kernel<<<(T_TOK * NHEAD * HALFD + 255) / 256, blk, 0, stream>>>(qkvf, rpe);
        attn_kernel<<<dim3(NWIN, NHEAD), blk, 0, stream>>>(qkvf, o_b);
        gemm(o_b, proj_t, proj_b + l * DMODEL, h, h, T_TOK, DMODEL, DMODEL, DMODEL);

        rmsnorm_kernel<<<T_TOK, blk, 0, stream>>>(h, norm2_s + l * DMODEL, n_b, DMODEL);
        gemm(n_b, gate_t, gate_b + l * FFDIM, nullptr, gf,
             T_TOK, FFDIM, FF_PAD, DMODEL);
        gemm(n_b, up_t, up_b + l * FFDIM, nullptr, uf,
             T_TOK, FFDIM, FF_PAD, DMODEL);
        silumul_kernel<<<(T_TOK * FFK_PAD + 255) / 256, blk, 0, stream>>>(gf, uf, g_b);
        gemm(g_b, down_t, down_b + l * DMODEL, h, h, T_TOK, DMODEL, DMODEL, FFK_PAD);
    }

    rmsnorm_kernel<<<T_TOK, blk, 0, stream>>>(h, lnq_s, n_b, DMODEL);
    // n_b viewed as [512, 5120]
    gemm(n_b, fc1_t, fc1_b, nullptr, fc1f, 512, MERGED, MERGED, MERGED);
    gelu_kernel<<<(512 * MERGED + 255) / 256, blk, 0, stream>>>(fc1f, m_b, 512 * MERGED);
    gemm(m_b, fc2_t, fc2_b, nullptr, out, 512, OUTD, OUTD, MERGED);
}

// Round 2
// 2029.678 us; speedup vs baseline: 1.1643x; 1.0058x over previous
//
#include <hip/hip_runtime.h>
#include <hip/hip_bf16.h>
#include <cstdint>
#include <cstddef>
#include <math.h>

#define T_TOK 2048
#define DMODEL 1280
#define NHEAD 16
#define HDIM 80
#define HALFD 40
#define FFDIM 3420
#define FF_PAD 3456        /* 27*128, N-pad for gate/up GEMM C */
#define FFK_PAD 3424       /* 107*32, K-pad for down GEMM A    */
#define PATCH_INDIM 1176
#define PATCHK_PAD 1184    /* 37*32 */
#define DEPTH_L 4
#define OUTD 3584
#define WIN 64
#define NWIN (T_TOK / WIN)
#define MERGED 5120
#define EPSV 1e-6f
#define SCALE_ATTN 0.11180339887498949f

typedef __attribute__((ext_vector_type(8))) short short8;
typedef __attribute__((ext_vector_type(4))) float f32x4;
typedef unsigned short ushort_t;

// ---------------------------------------------------------------------------
// bf16 MFMA GEMM, pipelined:  C[M,Nc]fp32 = A[M,Kp]bf16 @ Bt[N,Kp]bf16^T
// BM=128, BN template {128,64}. 256 thr = 4 waves.
//   BN=128: waves 2x2, wave tile 64x64 (4x4 MFMA), LDS 48 KiB. For the
//           fetch-heavy fc1/fc2 shapes (max B reuse).
//   BN=64 : waves 4x1 on M, wave tile 32x64 (2x4 MFMA), LDS 36 KiB. For the
//           L3-resident layer GEMMs — doubles the grid (occupancy was the
//           limiter at 0.6-1.9 blocks/CU).
// 3-stage LDS triple-buffer, 2-tiles-ahead prefetch, counted s_waitcnt
// vmcnt(NV) + raw s_barrier (loads stay in flight across barriers; each wave
// drains its own tile-t loads BEFORE the barrier, so barrier-exit implies the
// tile is fully written by all waves). T5 setprio around the MFMA cluster.
// NO XCD remap: round-1 measured it doubling FETCH_SIZE (L2 working set per
// XCD ballooned with fully co-resident grids); default dispatch is better.
// Requires M%128==0, Nc%BN==0, Kp%32==0. Epilogue guarded by col<Nreal.
// ---------------------------------------------------------------------------
template<int BN>
__global__ __launch_bounds__(256) void gemm_bf16(
    const ushort_t* __restrict__ A, const ushort_t* __restrict__ Bt,
    const float* __restrict__ bias, const float* __restrict__ res,
    float* __restrict__ C, int M, int Nreal, int Nc, int Kp)
{
    constexpr int MI = (BN == 128) ? 4 : 2;   // acc row-frags per wave
    __shared__ ushort_t As[3][128 * 32];
    __shared__ ushort_t Bs[3][BN * 32];

    const int tid  = threadIdx.x;
    const int lane = tid & 63;
    const int wave = tid >> 6;

    const int row0 = blockIdx.y * 128;
    const int col0 = blockIdx.x * BN;
    const int wm0  = (BN == 128) ? (wave & 1) * 64 : wave * 32;
    const int wn0  = (BN == 128) ? (wave >> 1) * 64 : 0;

    f32x4 acc[MI][4] = {};

    const int ldr = tid >> 2;                       // 0..63 staging row
    const int ldc = ((tid & 3) ^ (ldr & 3)) * 8;    // pre-swizzled source chunk

    const int mrow = lane & 15;
    const int kswz = ((lane >> 4) ^ (mrow & 3)) * 8; // matching read swizzle
    const int nt   = Kp >> 5;

    auto stage = [&](int buf, int kk) {
        const ushort_t* ga = A  + (size_t)(row0 + ldr) * Kp + kk + ldc;
        __builtin_amdgcn_global_load_lds(
            (const __attribute__((address_space(1))) void*)ga,
            (__attribute__((address_space(3))) void*)(&As[buf][tid * 8]), 16, 0, 0);
        __builtin_amdgcn_global_load_lds(
            (const __attribute__((address_space(1))) void*)(ga + (size_t)64 * Kp),
            (__attribute__((address_space(3))) void*)(&As[buf][2048 + tid * 8]), 16, 0, 0);
        const ushort_t* gb = Bt + (size_t)(col0 + ldr) * Kp + kk + ldc;
        __builtin_amdgcn_global_load_lds(
            (const __attribute__((address_space(1))) void*)gb,
            (__attribute__((address_space(3))) void*)(&Bs[buf][tid * 8]), 16, 0, 0);
        if constexpr (BN == 128) {
            __builtin_amdgcn_global_load_lds(
                (const __attribute__((address_space(1))) void*)(gb + (size_t)64 * Kp),
                (__attribute__((address_space(3))) void*)(&Bs[buf][2048 + tid * 8]), 16, 0, 0);
        }
    };

    // Prologue: stage tiles 0 and 1 (NV vm ops each)
    stage(0, 0);
    if (nt > 1) stage(1, 32);

    int cur = 0;
    for (int t = 0; t < nt; ++t) {
        // Wait for tile t only (its NV loads are the oldest); keep tile t+1's
        // NV loads in flight across the barrier.
        if (t + 1 < nt) {
            if constexpr (BN == 128) asm volatile("s_waitcnt vmcnt(4)" ::: "memory");
            else                     asm volatile("s_waitcnt vmcnt(3)" ::: "memory");
        } else {
            asm volatile("s_waitcnt vmcnt(0)" ::: "memory");
        }
        __builtin_amdgcn_s_barrier();

        short8 af[MI], bf[4];
        #pragma unroll
        for (int i = 0; i < MI; i++)
            af[i] = *(const short8*)&As[cur][(wm0 + i * 16 + mrow) * 32 + kswz];
        #pragma unroll
        for (int j = 0; j < 4; j++)
            bf[j] = *(const short8*)&Bs[cur][(wn0 + j * 16 + mrow) * 32 + kswz];

        __builtin_amdgcn_s_setprio(1);
        #pragma unroll
        for (int i = 0; i < MI; i++)
            #pragma unroll
            for (int j = 0; j < 4; j++)
                acc[i][j] = __builtin_amdgcn_mfma_f32_16x16x32_bf16(
                    af[i], bf[j], acc[i][j], 0, 0, 0);
        __builtin_amdgcn_s_setprio(0);

        // Prefetch tile t+2 into buf (t+2)%3 (last read in iter t-1; all waves
        // passed this iter's barrier so nobody still reads it).
        if (t + 2 < nt) {
            int pf = cur + 2; if (pf >= 3) pf -= 3;
            stage(pf, (t + 2) * 32);
        }
        cur = (cur == 2) ? 0 : cur + 1;
    }

    const int crow0 = row0 + wm0 + (lane >> 4) * 4;
    const int ccol0 = col0 + wn0 + (lane & 15);
    #pragma unroll
    for (int j = 0; j < 4; j++) {
        const int col = ccol0 + j * 16;
        if (col >= Nreal) continue;
        const float bv = bias ? bias[col] : 0.f;
        #pragma unroll
        for (int i = 0; i < MI; i++) {
            #pragma unroll
            for (int r = 0; r < 4; r++) {
                const int row = crow0 + i * 16 + r;
                float v = acc[i][j][r] + bv;
                if (res) v += res[(size_t)row * Nc + col];
                C[(size_t)row * Nc + col] = v;
            }
        }
    }
}

// ---------------------------------------------------------------------------
// Tiled transpose + fp32->bf16: in[K,N] fp32 -> out[Np,Kp] bf16 (zero-padded)
// ---------------------------------------------------------------------------
__global__ __launch_bounds__(256) void transpose_cvt(
    const float* __restrict__ in, __hip_bfloat16* __restrict__ out,
    int K, int N, int Kp, int Np)
{
    __shared__ float t[32][33];
    const int k0 = blockIdx.x * 32, n0 = blockIdx.y * 32;
    const int tx = threadIdx.x & 31, ty = threadIdx.x >> 5;  // 32x8
    #pragma unroll
    for (int i = 0; i < 4; i++) {
        const int k = k0 + ty + i * 8, n = n0 + tx;
        t[ty + i * 8][tx] = (k < K && n < N) ? in[(size_t)k * N + n] : 0.f;
    }
    __syncthreads();
    #pragma unroll
    for (int i = 0; i < 4; i++) {
        const int n = n0 + ty + i * 8, k = k0 + tx;
        if (n < Np && k < Kp)
            out[(size_t)n * Kp + k] = __float2bfloat16(t[tx][ty + i * 8]);
    }
}

// fp32 [M,K] -> bf16 [M,Kp] with zero pad (row-major, no transpose)
__global__ __launch_bounds__(256) void cvt_pad(
    const float* __restrict__ in, __hip_bfloat16* __restrict__ out,
    int M, int K, int Kp)
{
    const int i = blockIdx.x * 256 + threadIdx.x;
    if (i >= M * Kp) return;
    const int m = i / Kp, k = i - m * Kp;
    out[i] = __float2bfloat16(k < K ? in[(size_t)m * K + k] : 0.f);
}

// ---------------------------------------------------------------------------
// RMSNorm fp32 in -> bf16 out. One block per row.
// ---------------------------------------------------------------------------
__global__ __launch_bounds__(256) void rmsnorm_kernel(
    const float* __restrict__ x, const float* __restrict__ scale,
    __hip_bfloat16* __restrict__ out, int D)
{
    const int row = blockIdx.x;
    const float* xr = x + (size_t)row * D;
    float ss = 0.f;
    for (int i = threadIdx.x; i < D; i += 256) { const float v = xr[i]; ss += v * v; }
    for (int off = 32; off > 0; off >>= 1) ss += __shfl_down(ss, off);
    __shared__ float red[4];
    if ((threadIdx.x & 63) == 0) red[threadIdx.x >> 6] = ss;
    __syncthreads();
    const float tot = red[0] + red[1] + red[2] + red[3];
    const float inv = rsqrtf(tot / (float)D + EPSV);
    __hip_bfloat16* orow = out + (size_t)row * D;
    for (int i = threadIdx.x; i < D; i += 256)
        orow[i] = __float2bfloat16(xr[i] * scale[i] * inv);
}

// ---------------------------------------------------------------------------
// RoPE in-place on fp32 qkv (T, 3*D)
// ---------------------------------------------------------------------------
__global__ __launch_bounds__(256) void rope_kernel(
    float* __restrict__ qkv, const float* __restrict__ rpe)
{
    const int i = blockIdx.x * 256 + threadIdx.x;
    if (i >= T_TOK * NHEAD * HALFD) return;
    const int t = i / (NHEAD * HALFD);
    const int rem = i - t * (NHEAD * HALFD);
    const int hh = rem / HALFD;
    const int j = rem - hh * HALFD;
    const float ang = rpe[t * HALFD + j];
    const float c = cosf(ang), s = sinf(ang);
    const size_t qb = (size_t)t * (3 * DMODEL) + hh * HDIM + j;
    float r = qkv[qb], im = qkv[qb + HALFD];
    qkv[qb] = r * c - im * s;
    qkv[qb + HALFD] = r * s + im * c;
    const size_t kb = qb + DMODEL;
    r = qkv[kb]; im = qkv[kb + HALFD];
    qkv[kb] = r * c - im * s;
    qkv[kb + HALFD] = r * s + im * c;
}

// ---------------------------------------------------------------------------
// Windowed attention (fp32 math), writes bf16 o. One block per (window, head).
// ---------------------------------------------------------------------------
__global__ __launch_bounds__(256) void attn_kernel(
    const float* __restrict__ qkv, __hip_bfloat16* __restrict__ o)
{
    __shared__ float qs[WIN][HDIM + 1];
    __shared__ float ks[WIN][HDIM + 1];   // reused for v
    __shared__ float ps[WIN][WIN];
    const int win = blockIdx.x, hh = blockIdx.y;
    const int t0 = win * WIN;
    const int tid = threadIdx.x;

    for (int i = tid; i < WIN * HDIM; i += 256) {
        const int r = i / HDIM, d = i - r * HDIM;
        const size_t base = (size_t)(t0 + r) * (3 * DMODEL) + hh * HDIM + d;
        qs[r][d] = qkv[base];
        ks[r][d] = qkv[base + DMODEL];
    }
    __syncthreads();

    const int row = tid >> 2, sub = tid & 3;
    float s[16];
    #pragma unroll
    for (int jj = 0; jj < 16; jj++) s[jj] = 0.f;
    for (int d = 0; d < HDIM; d++) {
        const float qv = qs[row][d];
        #pragma unroll
        for (int jj = 0; jj < 16; jj++) s[jj] += qv * ks[sub * 16 + jj][d];
    }
    float mx = -1e30f;
    #pragma unroll
    for (int jj = 0; jj < 16; jj++) { s[jj] *= SCALE_ATTN; mx = fmaxf(mx, s[jj]); }
    for (int off = 1; off < 4; off <<= 1) mx = fmaxf(mx, __shfl_xor(mx, off));
    float l = 0.f;
    #pragma unroll
    for (int jj = 0; jj < 16; jj++) { s[jj] = expf(s[jj] - mx); l += s[jj]; }
    for (int off = 1; off < 4; off <<= 1) l += __shfl_xor(l, off);
    const float inv = 1.f / l;
    #pragma unroll
    for (int jj = 0; jj < 16; jj++) ps[row][sub * 16 + jj] = s[jj] * inv;
    __syncthreads();

    for (int i = tid; i < WIN * HDIM; i += 256) {
        const int r = i / HDIM, d = i - r * HDIM;
        ks[r][d] = qkv[(size_t)(t0 + r) * (3 * DMODEL) + 2 * DMODEL + hh * HDIM + d];
    }
    __syncthreads();

    for (int i = tid; i < WIN * HDIM; i += 256) {
        const int r = i / HDIM, d = i - r * HDIM;
        float acc = 0.f;
        #pragma unroll
        for (int j = 0; j < WIN; j++) acc += ps[r][j] * ks[j][d];
        o[(size_t)(t0 + r) * DMODEL + hh * HDIM + d] = __float2bfloat16(acc);
    }
}

// ---------------------------------------------------------------------------
// silu(g)*u: g,u fp32 [T, FF_PAD] (cols<FFDIM valid) -> bf16 [T, FFK_PAD]
// ---------------------------------------------------------------------------
__global__ __launch_bounds__(256) void silumul_kernel(
    const float* __restrict__ g, const float* __restrict__ u,
    __hip_bfloat16* __restrict__ out)
{
    const int i = blockIdx.x * 256 + threadIdx.x;
    if (i >= T_TOK * FFK_PAD) return;
    const int row = i / FFK_PAD, k = i - row * FFK_PAD;
    float v = 0.f;
    if (k < FFDIM) {
        const float x = g[(size_t)row * FF_PAD + k];
        v = (x / (1.f + expf(-x))) * u[(size_t)row * FF_PAD + k];
    }
    out[i] = __float2bfloat16(v);
}

// gelu exact on fp32 [n] -> bf16 [n]
__global__ __launch_bounds__(256) void gelu_kernel(
    const float* __restrict__ x, __hip_bfloat16* __restrict__ out, int n)
{
    const int i = blockIdx.x * 256 + threadIdx.x;
    if (i < n) {
        const float v = x[i];
        out[i] = __float2bfloat16(0.5f * v * (1.f + erff(v * 0.70710678118654752f)));
    }
}

// ---------------------------------------------------------------------------
extern "C" void kernel_launch(void* const* d_in, const int* in_sizes, int n_in,
                              void* d_out, int out_size, void* d_ws, size_t ws_size,
                              hipStream_t stream)
{
    const float* x       = (const float*)d_in[0];
    const float* rpe     = (const float*)d_in[1];
    const float* patch_w = (const float*)d_in[3];
    const float* qkv_w   = (const float*)d_in[4];
    const float* qkv_b   = (const float*)d_in[5];
    const float* proj_w  = (const float*)d_in[6];
    const float* proj_b  = (const float*)d_in[7];
    const float* norm1_s = (const float*)d_in[8];
    const float* norm2_s = (const float*)d_in[9];
    const float* gate_w  = (const float*)d_in[10];
    const float* gate_b  = (const float*)d_in[11];
    const float* up_w    = (const float*)d_in[12];
    const float* up_b    = (const float*)d_in[13];
    const float* down_w  = (const float*)d_in[14];
    const float* down_b  = (const float*)d_in[15];
    const float* lnq_s   = (const float*)d_in[16];
    const float* fc1_w   = (const float*)d_in[17];
    const float* fc1_b   = (const float*)d_in[18];
    const float* fc2_w   = (const float*)d_in[19];
    const float* fc2_b   = (const float*)d_in[20];
    float* out = (float*)d_out;

    char* p = (char*)d_ws;
    auto alloc = [&](size_t bytes) -> void* {
        void* r = (void*)p; p += (bytes + 255) & ~(size_t)255; return r;
    };
    // fp32 buffers
    float* h    = (float*)alloc((size_t)T_TOK * DMODEL * 4);
    float* qkvf = (float*)alloc((size_t)T_TOK * 3 * DMODEL * 4);
    float* gf   = (float*)alloc((size_t)T_TOK * FF_PAD * 4);
    float* uf   = (float*)alloc((size_t)T_TOK * FF_PAD * 4);
    float* fc1f = (float*)alloc((size_t)512 * MERGED * 4);
    // bf16 buffers
    __hip_bfloat16* x_b    = (__hip_bfloat16*)alloc((size_t)T_TOK * PATCHK_PAD * 2);
    __hip_bfloat16* n_b    = (__hip_bfloat16*)alloc((size_t)T_TOK * DMODEL * 2);
    __hip_bfloat16* o_b    = (__hip_bfloat16*)alloc((size_t)T_TOK * DMODEL * 2);
    __hip_bfloat16* g_b    = (__hip_bfloat16*)alloc((size_t)T_TOK * FFK_PAD * 2);
    __hip_bfloat16* m_b    = (__hip_bfloat16*)alloc((size_t)512 * MERGED * 2);
    __hip_bfloat16* patch_t= (__hip_bfloat16*)alloc((size_t)DMODEL * PATCHK_PAD * 2);
    __hip_bfloat16* qkv_t  = (__hip_bfloat16*)alloc((size_t)3 * DMODEL * DMODEL * 2);
    __hip_bfloat16* proj_t = (__hip_bfloat16*)alloc((size_t)DMODEL * DMODEL * 2);
    __hip_bfloat16* gate_t = (__hip_bfloat16*)alloc((size_t)FF_PAD * DMODEL * 2);
    __hip_bfloat16* up_t   = (__hip_bfloat16*)alloc((size_t)FF_PAD * DMODEL * 2);
    __hip_bfloat16* down_t = (__hip_bfloat16*)alloc((size_t)DMODEL * FFK_PAD * 2);
    __hip_bfloat16* fc1_t  = (__hip_bfloat16*)alloc((size_t)MERGED * MERGED * 2);
    __hip_bfloat16* fc2_t  = (__hip_bfloat16*)alloc((size_t)OUTD * MERGED * 2);

    const dim3 blk(256);
    // bn=64: layer GEMMs (B fits L3; occupancy-limited -> double the grid)
    // bn=128: fc1/fc2 (fetch-heavy; keep max B reuse)
    auto gemm = [&](const __hip_bfloat16* A, const __hip_bfloat16* Bt,
                    const float* bias, const float* res, float* C,
                    int M, int Nreal, int Nc, int Kp, int bn) {
        if (bn == 64) {
            dim3 grid(Nc / 64, M / 128);
            gemm_bf16<64><<<grid, blk, 0, stream>>>((const ushort_t*)A, (const ushort_t*)Bt,
                                                    bias, res, C, M, Nreal, Nc, Kp);
        } else {
            dim3 grid(Nc / 128, M / 128);
            gemm_bf16<128><<<grid, blk, 0, stream>>>((const ushort_t*)A, (const ushort_t*)Bt,
                                                     bias, res, C, M, Nreal, Nc, Kp);
        }
    };
    auto tcvt = [&](const float* in, __hip_bfloat16* o2, int K, int N, int Kp, int Np) {
        dim3 grid((Kp + 31) / 32, (Np + 31) / 32);
        transpose_cvt<<<grid, blk, 0, stream>>>(in, o2, K, N, Kp, Np);
    };

    // one-time (per call) conversions
    cvt_pad<<<(T_TOK * PATCHK_PAD + 255) / 256, blk, 0, stream>>>(
        x, x_b, T_TOK, PATCH_INDIM, PATCHK_PAD);
    tcvt(patch_w, patch_t, PATCH_INDIM, DMODEL, PATCHK_PAD, DMODEL);
    tcvt(fc1_w, fc1_t, MERGED, MERGED, MERGED, MERGED);
    tcvt(fc2_w, fc2_t, MERGED, OUTD, MERGED, OUTD);

    // h = x @ patch_w
    gemm(x_b, patch_t, nullptr, nullptr, h, T_TOK, DMODEL, DMODEL, PATCHK_PAD, 64);

    for (int l = 0; l < DEPTH_L; l++) {
        tcvt(qkv_w + (size_t)l * DMODEL * 3 * DMODEL, qkv_t, DMODEL, 3 * DMODEL,
             DMODEL, 3 * DMODEL);
        tcvt(proj_w + (size_t)l * DMODEL * DMODEL, proj_t, DMODEL, DMODEL,
             DMODEL, DMODEL);
        tcvt(gate_w + (size_t)l * DMODEL * FFDIM, gate_t, DMODEL, FFDIM,
             DMODEL, FF_PAD);
        tcvt(up_w + (size_t)l * DMODEL * FFDIM, up_t, DMODEL, FFDIM,
             DMODEL, FF_PAD);
        tcvt(down_w + (size_t)l * FFDIM * DMODEL, down_t, FFDIM, DMODEL,
             FFK_PAD, DMODEL);

        rmsnorm_kernel<<<T_TOK, blk, 0, stream>>>(h, norm1_s + l * DMODEL, n_b, DMODEL);
        gemm(n_b, qkv_t, qkv_b + l * 3 * DMODEL, nullptr, qkvf,
             T_TOK, 3 * DMODEL, 3 * DMODEL, DMODEL, 64);
        rope_kernel<<<(T_TOK * NHEAD * HALFD + 255) / 256, blk, 0, stream>>>(qkvf, rpe);
        attn_kernel<<<dim3(NWIN, NHEAD), blk, 0, stream>>>(qkvf, o_b);
        gemm(o_b, proj_t, proj_b + l * DMODEL, h, h, T_TOK, DMODEL, DMODEL, DMODEL, 64);

        rmsnorm_kernel<<<T_TOK, blk, 0, stream>>>(h, norm2_s + l * DMODEL, n_b, DMODEL);
        gemm(n_b, gate_t, gate_b + l * FFDIM, nullptr, gf,
             T_TOK, FFDIM, FF_PAD, DMODEL, 64);
        gemm(n_b, up_t, up_b + l * FFDIM, nullptr, uf,
             T_TOK, FFDIM, FF_PAD, DMODEL, 64);
        silumul_kernel<<<(T_TOK * FFK_PAD + 255) / 256, blk, 0, stream>>>(gf, uf, g_b);
        gemm(g_b, down_t, down_b + l * DMODEL, h, h, T_TOK, DMODEL, DMODEL, FFK_PAD, 64);
    }

    rmsnorm_kernel<<<T_TOK, blk, 0, stream>>>(h, lnq_s, n_b, DMODEL);
    // n_b viewed as [512, 5120]
    gemm(n_b, fc1_t, fc1_b, nullptr, fc1f, 512, MERGED, MERGED, MERGED, 128);
    gelu_kernel<<<(512 * MERGED + 255) / 256, blk, 0, stream>>>(fc1f, m_b, 512 * MERGED);
    gemm(m_b, fc2_t, fc2_b, nullptr, out, 512, OUTD, OUTD, MERGED, 128);
}

// Round 3
// 1819.217 us; speedup vs baseline: 1.2990x; 1.1157x over previous
//
#include <hip/hip_runtime.h>
#include <hip/hip_bf16.h>
#include <cstdint>
#include <cstddef>
#include <math.h>

#define T_TOK 2048
#define DMODEL 1280
#define NHEAD 16
#define HDIM 80
#define HALFD 40
#define FFDIM 3420
#define FF_PAD 3456        /* 27*128, N-pad for gate/up GEMM C */
#define GU_N (2 * FF_PAD)  /* 6912: fused gate|up GEMM width   */
#define FFK_PAD 3424       /* 107*32, K-pad for down GEMM A    */
#define PATCH_INDIM 1176
#define PATCHK_PAD 1184    /* 37*32 */
#define DEPTH_L 4
#define OUTD 3584
#define WIN 64
#define NWIN (T_TOK / WIN)
#define MERGED 5120
#define EPSV 1e-6f
#define SCALE_ATTN 0.11180339887498949f

typedef __attribute__((ext_vector_type(8))) short short8;
typedef __attribute__((ext_vector_type(4))) float f32x4;
typedef unsigned short ushort_t;

// ---------------------------------------------------------------------------
// bf16 MFMA GEMM, pipelined + optional split-K (blockIdx.z = K-slice):
//   S==1 : C[M,Nc]fp32 = A@Bt^T (+bias, +res)   — direct epilogue
//   S>1  : partials[z][M,Nc] = A@Bt^T over K-slice z — plain store, a
//          reduce kernel sums slices (+bias/+res/activation) afterwards.
// BM=BN=128, 256 thr = 4 waves (2x2), wave tile 64x64 (4x4 16x16x32 MFMA).
// 3-stage LDS triple-buffer (48 KiB), 2-tiles-ahead prefetch, counted
// s_waitcnt vmcnt(4) + raw s_barrier (loads stay in flight across barriers;
// each wave drains its OWN tile-t loads before the barrier, so barrier-exit
// implies the tile is fully written by all waves). setprio around MFMA.
// Rationale (r2 counters): small-grid GEMMs (160 blocks) pin Occupancy at 7%
// — grid size is the cap, so split-K grows the grid; fetch is NOT the limit
// (fc1 ran at 1.1 TB/s with doubled fetch, same dur).
// Requires M%128==0, Nc%128==0, Kp%32==0. Split callers use Nreal==Nc.
// ---------------------------------------------------------------------------
template<int BN>
__global__ __launch_bounds__(256) void gemm_bf16(
    const ushort_t* __restrict__ A, const ushort_t* __restrict__ Bt,
    const float* __restrict__ bias, const float* __restrict__ res,
    float* __restrict__ C, int M, int Nreal, int Nc, int Kp)
{
    constexpr int MI = (BN == 128) ? 4 : 2;
    __shared__ ushort_t As[3][128 * 32];
    __shared__ ushort_t Bs[3][BN * 32];

    const int tid  = threadIdx.x;
    const int lane = tid & 63;
    const int wave = tid >> 6;

    const int row0 = blockIdx.y * 128;
    const int col0 = blockIdx.x * BN;
    const int wm0  = (BN == 128) ? (wave & 1) * 64 : wave * 32;
    const int wn0  = (BN == 128) ? (wave >> 1) * 64 : 0;

    f32x4 acc[MI][4] = {};

    const int ldr = tid >> 2;                       // 0..63 staging row
    const int ldc = ((tid & 3) ^ (ldr & 3)) * 8;    // pre-swizzled source chunk

    const int mrow = lane & 15;
    const int kswz = ((lane >> 4) ^ (mrow & 3)) * 8; // matching read swizzle

    // split-K tile range for this z-slice
    const int nt_all = Kp >> 5;
    const int S   = gridDim.z;
    const int per = (nt_all + S - 1) / S;
    const int tA  = blockIdx.z * per;
    const int tE  = (tA + per < nt_all) ? (tA + per) : nt_all;
    const int cnt = tE - tA;

    auto stage = [&](int buf, int kk) {
        const ushort_t* ga = A  + (size_t)(row0 + ldr) * Kp + kk + ldc;
        __builtin_amdgcn_global_load_lds(
            (const __attribute__((address_space(1))) void*)ga,
            (__attribute__((address_space(3))) void*)(&As[buf][tid * 8]), 16, 0, 0);
        __builtin_amdgcn_global_load_lds(
            (const __attribute__((address_space(1))) void*)(ga + (size_t)64 * Kp),
            (__attribute__((address_space(3))) void*)(&As[buf][2048 + tid * 8]), 16, 0, 0);
        const ushort_t* gb = Bt + (size_t)(col0 + ldr) * Kp + kk + ldc;
        __builtin_amdgcn_global_load_lds(
            (const __attribute__((address_space(1))) void*)gb,
            (__attribute__((address_space(3))) void*)(&Bs[buf][tid * 8]), 16, 0, 0);
        if constexpr (BN == 128) {
            __builtin_amdgcn_global_load_lds(
                (const __attribute__((address_space(1))) void*)(gb + (size_t)64 * Kp),
                (__attribute__((address_space(3))) void*)(&Bs[buf][2048 + tid * 8]), 16, 0, 0);
        }
    };

    if (cnt > 0) {
        // Prologue: stage first two tiles of this slice
        stage(0, tA * 32);
        if (cnt > 1) stage(1, (tA + 1) * 32);

        int cur = 0;
        for (int t = 0; t < cnt; ++t) {
            // Wait for tile t only (its loads are the oldest); keep tile t+1's
            // loads in flight across the barrier.
            if (t + 1 < cnt) {
                if constexpr (BN == 128) asm volatile("s_waitcnt vmcnt(4)" ::: "memory");
                else                     asm volatile("s_waitcnt vmcnt(3)" ::: "memory");
            } else {
                asm volatile("s_waitcnt vmcnt(0)" ::: "memory");
            }
            __builtin_amdgcn_s_barrier();

            short8 af[MI], bf[4];
            #pragma unroll
            for (int i = 0; i < MI; i++)
                af[i] = *(const short8*)&As[cur][(wm0 + i * 16 + mrow) * 32 + kswz];
            #pragma unroll
            for (int j = 0; j < 4; j++)
                bf[j] = *(const short8*)&Bs[cur][(wn0 + j * 16 + mrow) * 32 + kswz];

            __builtin_amdgcn_s_setprio(1);
            #pragma unroll
            for (int i = 0; i < MI; i++)
                #pragma unroll
                for (int j = 0; j < 4; j++)
                    acc[i][j] = __builtin_amdgcn_mfma_f32_16x16x32_bf16(
                        af[i], bf[j], acc[i][j], 0, 0, 0);
            __builtin_amdgcn_s_setprio(0);

            // Prefetch tile t+2 into buf (t+2)%3 (all waves passed this iter's
            // barrier, so nobody still reads it).
            if (t + 2 < cnt) {
                int pf = cur + 2; if (pf >= 3) pf -= 3;
                stage(pf, (tA + t + 2) * 32);
            }
            cur = (cur == 2) ? 0 : cur + 1;
        }
    }

    const int crow0 = row0 + wm0 + (lane >> 4) * 4;
    const int ccol0 = col0 + wn0 + (lane & 15);
    if (gridDim.z > 1) {
        // split-K partial store (no bias/res; reduce kernel finishes)
        float* Cz = C + (size_t)blockIdx.z * ((size_t)M * Nc);
        #pragma unroll
        for (int j = 0; j < 4; j++) {
            const int col = ccol0 + j * 16;
            #pragma unroll
            for (int i = 0; i < MI; i++)
                #pragma unroll
                for (int r = 0; r < 4; r++)
                    Cz[(size_t)(crow0 + i * 16 + r) * Nc + col] = acc[i][j][r];
        }
    } else {
        #pragma unroll
        for (int j = 0; j < 4; j++) {
            const int col = ccol0 + j * 16;
            if (col >= Nreal) continue;
            const float bv = bias ? bias[col] : 0.f;
            #pragma unroll
            for (int i = 0; i < MI; i++) {
                #pragma unroll
                for (int r = 0; r < 4; r++) {
                    const int row = crow0 + i * 16 + r;
                    float v = acc[i][j][r] + bv;
                    if (res) v += res[(size_t)row * Nc + col];
                    C[(size_t)row * Nc + col] = v;
                }
            }
        }
    }
}

// ---------------------------------------------------------------------------
// Split-K reduce: out[e] = (res?res[e]:0) + (bias?bias[e%Nc]:0) + sum_z p[z][e]
// f32x4 vectorized; Nc % 4 == 0 so the 4-chunk never crosses a row.
// ---------------------------------------------------------------------------
__global__ __launch_bounds__(256) void reduce_sum(
    const float* __restrict__ p, const float* __restrict__ bias,
    const float* __restrict__ res, float* __restrict__ out,
    int len4, int Nc, int S)
{
    const int i = blockIdx.x * 256 + threadIdx.x;
    if (i >= len4) return;
    const size_t e = (size_t)i * 4;
    const int col = (int)(e % (size_t)Nc);
    f32x4 acc = {0.f, 0.f, 0.f, 0.f};
    if (bias) acc += *(const f32x4*)&bias[col];
    if (res)  acc += *(const f32x4*)&res[e];
    const size_t stride = (size_t)len4 * 4;
    for (int z = 0; z < S; z++)
        acc += *(const f32x4*)&p[(size_t)z * stride + e];
    *(f32x4*)&out[e] = acc;
}

// Split-K reduce fused with exact gelu, bf16 out (fc1 epilogue).
__global__ __launch_bounds__(256) void reduce_gelu_bf16(
    const float* __restrict__ p, const float* __restrict__ bias,
    __hip_bfloat16* __restrict__ out, int len4, int Nc, int S)
{
    const int i = blockIdx.x * 256 + threadIdx.x;
    if (i >= len4) return;
    const size_t e = (size_t)i * 4;
    const int col = (int)(e % (size_t)Nc);
    f32x4 acc = *(const f32x4*)&bias[col];
    const size_t stride = (size_t)len4 * 4;
    for (int z = 0; z < S; z++)
        acc += *(const f32x4*)&p[(size_t)z * stride + e];
    #pragma unroll
    for (int q = 0; q < 4; q++) {
        const float v = acc[q];
        out[e + q] = __float2bfloat16(0.5f * v * (1.f + erff(v * 0.70710678118654752f)));
    }
}

// ---------------------------------------------------------------------------
// Tiled transpose + fp32->bf16: in[K,N] fp32 -> out[Np,Kp] bf16 (zero-padded)
// ---------------------------------------------------------------------------
__global__ __launch_bounds__(256) void transpose_cvt(
    const float* __restrict__ in, __hip_bfloat16* __restrict__ out,
    int K, int N, int Kp, int Np)
{
    __shared__ float t[32][33];
    const int k0 = blockIdx.x * 32, n0 = blockIdx.y * 32;
    const int tx = threadIdx.x & 31, ty = threadIdx.x >> 5;  // 32x8
    #pragma unroll
    for (int i = 0; i < 4; i++) {
        const int k = k0 + ty + i * 8, n = n0 + tx;
        t[ty + i * 8][tx] = (k < K && n < N) ? in[(size_t)k * N + n] : 0.f;
    }
    __syncthreads();
    #pragma unroll
    for (int i = 0; i < 4; i++) {
        const int n = n0 + ty + i * 8, k = k0 + tx;
        if (n < Np && k < Kp)
            out[(size_t)n * Kp + k] = __float2bfloat16(t[tx][ty + i * 8]);
    }
}

// fp32 [M,K] -> bf16 [M,Kp] with zero pad (row-major, no transpose)
__global__ __launch_bounds__(256) void cvt_pad(
    const float* __restrict__ in, __hip_bfloat16* __restrict__ out,
    int M, int K, int Kp)
{
    const int i = blockIdx.x * 256 + threadIdx.x;
    if (i >= M * Kp) return;
    const int m = i / Kp, k = i - m * Kp;
    out[i] = __float2bfloat16(k < K ? in[(size_t)m * K + k] : 0.f);
}

// ---------------------------------------------------------------------------
// RMSNorm fp32 in -> bf16 out. One block per row.
// ---------------------------------------------------------------------------
__global__ __launch_bounds__(256) void rmsnorm_kernel(
    const float* __restrict__ x, const float* __restrict__ scale,
    __hip_bfloat16* __restrict__ out, int D)
{
    const int row = blockIdx.x;
    const float* xr = x + (size_t)row * D;
    float ss = 0.f;
    for (int i = threadIdx.x; i < D; i += 256) { const float v = xr[i]; ss += v * v; }
    for (int off = 32; off > 0; off >>= 1) ss += __shfl_down(ss, off);
    __shared__ float red[4];
    if ((threadIdx.x & 63) == 0) red[threadIdx.x >> 6] = ss;
    __syncthreads();
    const float tot = red[0] + red[1] + red[2] + red[3];
    const float inv = rsqrtf(tot / (float)D + EPSV);
    __hip_bfloat16* orow = out + (size_t)row * D;
    for (int i = threadIdx.x; i < D; i += 256)
        orow[i] = __float2bfloat16(xr[i] * scale[i] * inv);
}

// ---------------------------------------------------------------------------
// RoPE in-place on fp32 qkv (T, 3*D)
// ---------------------------------------------------------------------------
__global__ __launch_bounds__(256) void rope_kernel(
    float* __restrict__ qkv, const float* __restrict__ rpe)
{
    const int i = blockIdx.x * 256 + threadIdx.x;
    if (i >= T_TOK * NHEAD * HALFD) return;
    const int t = i / (NHEAD * HALFD);
    const int rem = i - t * (NHEAD * HALFD);
    const int hh = rem / HALFD;
    const int j = rem - hh * HALFD;
    const float ang = rpe[t * HALFD + j];
    const float c = cosf(ang), s = sinf(ang);
    const size_t qb = (size_t)t * (3 * DMODEL) + hh * HDIM + j;
    float r = qkv[qb], im = qkv[qb + HALFD];
    qkv[qb] = r * c - im * s;
    qkv[qb + HALFD] = r * s + im * c;
    const size_t kb = qb + DMODEL;
    r = qkv[kb]; im = qkv[kb + HALFD];
    qkv[kb] = r * c - im * s;
    qkv[kb + HALFD] = r * s + im * c;
}

// ---------------------------------------------------------------------------
// Windowed attention (fp32 math), writes bf16 o. One block per (window, head).
// ---------------------------------------------------------------------------
__global__ __launch_bounds__(256) void attn_kernel(
    const float* __restrict__ qkv, __hip_bfloat16* __restrict__ o)
{
    __shared__ float qs[WIN][HDIM + 1];
    __shared__ float ks[WIN][HDIM + 1];   // reused for v
    __shared__ float ps[WIN][WIN];
    const int win = blockIdx.x, hh = blockIdx.y;
    const int t0 = win * WIN;
    const int tid = threadIdx.x;

    for (int i = tid; i < WIN * HDIM; i += 256) {
        const int r = i / HDIM, d = i - r * HDIM;
        const size_t base = (size_t)(t0 + r) * (3 * DMODEL) + hh * HDIM + d;
        qs[r][d] = qkv[base];
        ks[r][d] = qkv[base + DMODEL];
    }
    __syncthreads();

    const int row = tid >> 2, sub = tid & 3;
    float s[16];
    #pragma unroll
    for (int jj = 0; jj < 16; jj++) s[jj] = 0.f;
    for (int d = 0; d < HDIM; d++) {
        const float qv = qs[row][d];
        #pragma unroll
        for (int jj = 0; jj < 16; jj++) s[jj] += qv * ks[sub * 16 + jj][d];
    }
    float mx = -1e30f;
    #pragma unroll
    for (int jj = 0; jj < 16; jj++) { s[jj] *= SCALE_ATTN; mx = fmaxf(mx, s[jj]); }
    for (int off = 1; off < 4; off <<= 1) mx = fmaxf(mx, __shfl_xor(mx, off));
    float l = 0.f;
    #pragma unroll
    for (int jj = 0; jj < 16; jj++) { s[jj] = expf(s[jj] - mx); l += s[jj]; }
    for (int off = 1; off < 4; off <<= 1) l += __shfl_xor(l, off);
    const float inv = 1.f / l;
    #pragma unroll
    for (int jj = 0; jj < 16; jj++) ps[row][sub * 16 + jj] = s[jj] * inv;
    __syncthreads();

    for (int i = tid; i < WIN * HDIM; i += 256) {
        const int r = i / HDIM, d = i - r * HDIM;
        ks[r][d] = qkv[(size_t)(t0 + r) * (3 * DMODEL) + 2 * DMODEL + hh * HDIM + d];
    }
    __syncthreads();

    for (int i = tid; i < WIN * HDIM; i += 256) {
        const int r = i / HDIM, d = i - r * HDIM;
        float acc = 0.f;
        #pragma unroll
        for (int j = 0; j < WIN; j++) acc += ps[r][j] * ks[j][d];
        o[(size_t)(t0 + r) * DMODEL + hh * HDIM + d] = __float2bfloat16(acc);
    }
}

// ---------------------------------------------------------------------------
// silu(g+gb)*(u+ub) from fused gate|up GEMM output gu [T, GU_N] fp32
// (gate cols at 0.., up cols at FF_PAD..) -> bf16 [T, FFK_PAD]
// ---------------------------------------------------------------------------
__global__ __launch_bounds__(256) void silumul_kernel(
    const float* __restrict__ gu, const float* __restrict__ gb,
    const float* __restrict__ ub, __hip_bfloat16* __restrict__ out)
{
    const int i = blockIdx.x * 256 + threadIdx.x;
    if (i >= T_TOK * FFK_PAD) return;
    const int row = i / FFK_PAD, k = i - row * FFK_PAD;
    float v = 0.f;
    if (k < FFDIM) {
        const float g = gu[(size_t)row * GU_N + k] + gb[k];
        const float u = gu[(size_t)row * GU_N + FF_PAD + k] + ub[k];
        v = (g / (1.f + expf(-g))) * u;
    }
    out[i] = __float2bfloat16(v);
}

// ---------------------------------------------------------------------------
extern "C" void kernel_launch(void* const* d_in, const int* in_sizes, int n_in,
                              void* d_out, int out_size, void* d_ws, size_t ws_size,
                              hipStream_t stream)
{
    const float* x       = (const float*)d_in[0];
    const float* rpe     = (const float*)d_in[1];
    const float* patch_w = (const float*)d_in[3];
    const float* qkv_w   = (const float*)d_in[4];
    const float* qkv_b   = (const float*)d_in[5];
    const float* proj_w  = (const float*)d_in[6];
    const float* proj_b  = (const float*)d_in[7];
    const float* norm1_s = (const float*)d_in[8];
    const float* norm2_s = (const float*)d_in[9];
    const float* gate_w  = (const float*)d_in[10];
    const float* gate_b  = (const float*)d_in[11];
    const float* up_w    = (const float*)d_in[12];
    const float* up_b    = (const float*)d_in[13];
    const float* down_w  = (const float*)d_in[14];
    const float* down_b  = (const float*)d_in[15];
    const float* lnq_s   = (const float*)d_in[16];
    const float* fc1_w   = (const float*)d_in[17];
    const float* fc1_b   = (const float*)d_in[18];
    const float* fc2_w   = (const float*)d_in[19];
    const float* fc2_b   = (const float*)d_in[20];
    float* out = (float*)d_out;

    char* p = (char*)d_ws;
    auto alloc = [&](size_t bytes) -> void* {
        void* r = (void*)p; p += (bytes + 255) & ~(size_t)255; return r;
    };
    // fp32 buffers
    float* h    = (float*)alloc((size_t)T_TOK * DMODEL * 4);
    float* qkvf = (float*)alloc((size_t)T_TOK * 3 * DMODEL * 4);
    float* guf  = (float*)alloc((size_t)T_TOK * GU_N * 4);          // fused gate|up C
    float* pbuf = (float*)alloc((size_t)4 * T_TOK * DMODEL * 4);    // split-K partials (max 4x2048x1280)
    // bf16 buffers
    __hip_bfloat16* x_b    = (__hip_bfloat16*)alloc((size_t)T_TOK * PATCHK_PAD * 2);
    __hip_bfloat16* n_b    = (__hip_bfloat16*)alloc((size_t)T_TOK * DMODEL * 2);
    __hip_bfloat16* o_b    = (__hip_bfloat16*)alloc((size_t)T_TOK * DMODEL * 2);
    __hip_bfloat16* g_b    = (__hip_bfloat16*)alloc((size_t)T_TOK * FFK_PAD * 2);
    __hip_bfloat16* m_b    = (__hip_bfloat16*)alloc((size_t)512 * MERGED * 2);
    __hip_bfloat16* patch_t= (__hip_bfloat16*)alloc((size_t)DMODEL * PATCHK_PAD * 2);
    __hip_bfloat16* qkv_t  = (__hip_bfloat16*)alloc((size_t)3 * DMODEL * DMODEL * 2);
    __hip_bfloat16* proj_t = (__hip_bfloat16*)alloc((size_t)DMODEL * DMODEL * 2);
    __hip_bfloat16* gu_t   = (__hip_bfloat16*)alloc((size_t)GU_N * DMODEL * 2);
    __hip_bfloat16* down_t = (__hip_bfloat16*)alloc((size_t)DMODEL * FFK_PAD * 2);
    __hip_bfloat16* fc1_t  = (__hip_bfloat16*)alloc((size_t)MERGED * MERGED * 2);
    __hip_bfloat16* fc2_t  = (__hip_bfloat16*)alloc((size_t)OUTD * MERGED * 2);

    const dim3 blk(256);
    auto gemm = [&](const __hip_bfloat16* A, const __hip_bfloat16* Bt,
                    const float* bias, const float* res, float* C,
                    int M, int Nreal, int Nc, int Kp, int S) {
        dim3 grid(Nc / 128, M / 128, S);
        gemm_bf16<128><<<grid, blk, 0, stream>>>((const ushort_t*)A, (const ushort_t*)Bt,
                                                 bias, res, C, M, Nreal, Nc, Kp);
    };
    auto tcvt = [&](const float* in, __hip_bfloat16* o2, int K, int N, int Kp, int Np) {
        dim3 grid((Kp + 31) / 32, (Np + 31) / 32);
        transpose_cvt<<<grid, blk, 0, stream>>>(in, o2, K, N, Kp, Np);
    };
    auto redsum = [&](const float* pp, const float* bias, const float* res,
                      float* o2, int len, int Nc, int S) {
        const int len4 = len / 4;
        reduce_sum<<<(len4 + 255) / 256, blk, 0, stream>>>(pp, bias, res, o2, len4, Nc, S);
    };

    // one-time (per call) conversions
    cvt_pad<<<(T_TOK * PATCHK_PAD + 255) / 256, blk, 0, stream>>>(
        x, x_b, T_TOK, PATCH_INDIM, PATCHK_PAD);
    tcvt(patch_w, patch_t, PATCH_INDIM, DMODEL, PATCHK_PAD, DMODEL);
    tcvt(fc1_w, fc1_t, MERGED, MERGED, MERGED, MERGED);
    tcvt(fc2_w, fc2_t, MERGED, OUTD, MERGED, OUTD);

    // h = x @ patch_w  (split-K=2: 320 blocks)
    gemm(x_b, patch_t, nullptr, nullptr, pbuf, T_TOK, DMODEL, DMODEL, PATCHK_PAD, 2);
    redsum(pbuf, nullptr, nullptr, h, T_TOK * DMODEL, DMODEL, 2);

    for (int l = 0; l < DEPTH_L; l++) {
        tcvt(qkv_w + (size_t)l * DMODEL * 3 * DMODEL, qkv_t, DMODEL, 3 * DMODEL,
             DMODEL, 3 * DMODEL);
        tcvt(proj_w + (size_t)l * DMODEL * DMODEL, proj_t, DMODEL, DMODEL,
             DMODEL, DMODEL);
        tcvt(gate_w + (size_t)l * DMODEL * FFDIM, gu_t, DMODEL, FFDIM,
             DMODEL, FF_PAD);
        tcvt(up_w + (size_t)l * DMODEL * FFDIM, gu_t + (size_t)FF_PAD * DMODEL,
             DMODEL, FFDIM, DMODEL, FF_PAD);
        tcvt(down_w + (size_t)l * FFDIM * DMODEL, down_t, FFDIM, DMODEL,
             FFK_PAD, DMODEL);

        rmsnorm_kernel<<<T_TOK, blk, 0, stream>>>(h, norm1_s + l * DMODEL, n_b, DMODEL);
        // qkv: 480 blocks already, keep direct epilogue
        gemm(n_b, qkv_t, qkv_b + l * 3 * DMODEL, nullptr, qkvf,
             T_TOK, 3 * DMODEL, 3 * DMODEL, DMODEL, 1);
        rope_kernel<<<(T_TOK * NHEAD * HALFD + 255) / 256, blk, 0, stream>>>(qkvf, rpe);
        attn_kernel<<<dim3(NWIN, NHEAD), blk, 0, stream>>>(qkvf, o_b);
        // proj: 160 blocks -> split-K=4 (640 blocks); reduce fuses bias + residual
        gemm(o_b, proj_t, nullptr, nullptr, pbuf, T_TOK, DMODEL, DMODEL, DMODEL, 4);
        redsum(pbuf, proj_b + l * DMODEL, h, h, T_TOK * DMODEL, DMODEL, 4);

        rmsnorm_kernel<<<T_TOK, blk, 0, stream>>>(h, norm2_s + l * DMODEL, n_b, DMODEL);
        // fused gate|up: one 864-block dispatch; biases folded into silumul
        gemm(n_b, gu_t, nullptr, nullptr, guf, T_TOK, GU_N, GU_N, DMODEL, 1);
        silumul_kernel<<<(T_TOK * FFK_PAD + 255) / 256, blk, 0, stream>>>(
            guf, gate_b + l * FFDIM, up_b + l * FFDIM, g_b);
        // down: 160 blocks -> split-K=4; reduce fuses bias + residual
        gemm(g_b, down_t, nullptr, nullptr, pbuf, T_TOK, DMODEL, DMODEL, FFK_PAD, 4);
        redsum(pbuf, down_b + l * DMODEL, h, h, T_TOK * DMODEL, DMODEL, 4);
    }

    rmsnorm_kernel<<<T_TOK, blk, 0, stream>>>(h, lnq_s, n_b, DMODEL);
    // n_b viewed as [512, 5120]; fc1: 160 -> 640 blocks, reduce fuses gelu->bf16
    gemm(n_b, fc1_t, nullptr, nullptr, pbuf, 512, MERGED, MERGED, MERGED, 4);
    {
        const int len4 = (512 * MERGED) / 4;
        reduce_gelu_bf16<<<(len4 + 255) / 256, blk, 0, stream>>>(
            pbuf, fc1_b, m_b, len4, MERGED, 4);
    }
    // fc2: 112 -> 448 blocks
    gemm(m_b, fc2_t, nullptr, nullptr, pbuf, 512, OUTD, OUTD, MERGED, 4);
    redsum(pbuf, fc2_b, nullptr, out, 512 * OUTD, OUTD, 4);
}